// Round 6
// baseline (240.227 us; speedup 1.0000x reference)
//
#include <hip/hip_runtime.h>

constexpr int BB   = 4;
constexpr int CCH  = 256;
constexpr int IDIM = 128;
constexpr int NAa  = 4096;
constexpr int NDd  = 16384;
constexpr int PAD  = 320;                 // aug dim 257 padded to 320
constexpr float NAinv = 1.0f / 4096.0f;

typedef __bf16 bf16x8 __attribute__((ext_vector_type(8)));
typedef float  f32x4  __attribute__((ext_vector_type(4)));

__device__ inline unsigned short f2bfu(float f) {
    unsigned u = __float_as_uint(f);
    u += 0x7FFFu + ((u >> 16) & 1u);      // RNE
    return (unsigned short)(u >> 16);
}

// ---- Phat (256x320, bf16) and RhatT (320x320, bf16, TRANSPOSED: [c2][k]) ----
__global__ __launch_bounds__(256) void k_prep(const float* __restrict__ qw,
                                              const float* __restrict__ gw,
                                              const float* __restrict__ gb,
                                              const float* __restrict__ thw,
                                              const float* __restrict__ thb,
                                              const float* __restrict__ phw,
                                              const float* __restrict__ phb,
                                              unsigned short* __restrict__ Ph,
                                              unsigned short* __restrict__ Rt) {
    const int idx = blockIdx.x * 256 + threadIdx.x;
    if (idx < CCH * PAD) {
        const int o = idx / PAD, c = idx - o * PAD;
        float acc = 0.f;
        if (c <= 256) {
            for (int i = 0; i < IDIM; ++i)
                acc += qw[o * IDIM + i] * ((c < 256) ? gw[i * CCH + c] : gb[i]);
        }
        Ph[idx] = f2bfu(acc);
    } else {
        const int id2 = idx - CCH * PAD;
        const int c2 = id2 / PAD, k = id2 - c2 * PAD;   // row c2, col k (transposed)
        float acc = 0.f;
        if (k <= 256 && c2 <= 256) {
            for (int i = 0; i < IDIM; ++i) {
                const float av = (k < 256) ? thw[i * CCH + k] : thb[i];
                const float bv = (c2 < 256) ? phw[i * CCH + c2] : phb[i];
                acc += av * bv;
            }
        }
        Rt[id2] = f2bfu(acc);
    }
}

// 16B-chunk XOR swizzle inside a 64x320 bf16 LDS tile (row-major, stride 320)
__device__ inline int at_idx(int row, int col) {
    return row * 320 + ((((col >> 3) ^ (row & 7)) << 3) | (col & 7));
}

// ---- k_V: V1 = Phat@Â, V2 = Rt@Â  (Â = [A;1;0...] 320x4096 per b, built
//      transposed in LDS per 64-col slice). grid (64, BB), block 256 (4 waves).
//      Each block: stage Âᵀ[n0..n0+63][0..319] -> 9 tasks (V1 m=0..3, V2 m=0..4). ----
__global__ __launch_bounds__(256) void k_V(const float* __restrict__ aim,
                                           const unsigned short* __restrict__ Ph,
                                           const unsigned short* __restrict__ Rt,
                                           unsigned short* __restrict__ V1,
                                           unsigned short* __restrict__ V2) {
    const int b = blockIdx.y, n0 = blockIdx.x * 64;
    const float* A = aim + (long)b * CCH * NAa;
    const int t = threadIdx.x, w = t >> 6, lane = t & 63, quad = lane >> 4, l16 = lane & 15;
    __shared__ __align__(16) unsigned short At[64 * 320];   // 40 KB, swizzled

    // stage: At[nn][c] = bf16(aim[c][n0+nn]), cols 0..255
    #pragma unroll 4
    for (int rep = 0; rep < 64; ++rep) {
        const int c = rep * 4 + w;
        At[at_idx(lane, c)] = f2bfu(A[(long)c * NAa + n0 + lane]);
    }
    // augmented cols: 256 -> 1.0, 257..319 -> 0
    {
        const int nn = t & 63, k0 = 256 + (t >> 6) * 16;
        #pragma unroll
        for (int k = k0; k < k0 + 16; ++k)
            At[at_idx(nn, k)] = (k == 256) ? (unsigned short)0x3F80u : (unsigned short)0u;
    }
    __syncthreads();

    for (int task = w; task < 9; task += 4) {
        const unsigned short* src;
        unsigned short* dst;
        int m0;
        if (task < 4) { m0 = task * 64;       src = Ph; dst = V1 + (long)b * CCH * NAa; }
        else          { m0 = (task - 4) * 64; src = Rt; dst = V2 + (long)b * PAD * NAa; }
        f32x4 acc[4][4] = {};
        for (int kt = 0; kt < PAD; kt += 32) {
            bf16x8 af[4], bfr[4];
            #pragma unroll
            for (int i = 0; i < 4; ++i)
                af[i] = *(const bf16x8*)(src + (long)(m0 + i * 16 + l16) * PAD + kt + quad * 8);
            #pragma unroll
            for (int j = 0; j < 4; ++j)
                bfr[j] = *(const bf16x8*)&At[at_idx(j * 16 + l16, kt + quad * 8)];
            #pragma unroll
            for (int i = 0; i < 4; ++i)
                #pragma unroll
                for (int j = 0; j < 4; ++j)
                    acc[i][j] = __builtin_amdgcn_mfma_f32_16x16x32_bf16(af[i], bfr[j], acc[i][j], 0, 0, 0);
        }
        #pragma unroll
        for (int i = 0; i < 4; ++i)
            #pragma unroll
            for (int j = 0; j < 4; ++j)
                #pragma unroll
                for (int reg = 0; reg < 4; ++reg)
                    dst[(long)(m0 + i * 16 + quad * 4 + reg) * NAa + n0 + j * 16 + l16] = f2bfu(acc[i][j][reg]);
    }
}

// ---- k_W: W5 = diag(s)/Na * (V1 @ V2ᵀ) + I ; col 256 -> b5.
//      grid (5, 4, BB), block 256 (4 waves, 4-way K-split of 4096 + LDS reduce). ----
__global__ __launch_bounds__(256) void k_W(const unsigned short* __restrict__ V1,
                                           const unsigned short* __restrict__ V2,
                                           const float* __restrict__ qb,
                                           const float* __restrict__ gamma,
                                           const float* __restrict__ beta,
                                           const float* __restrict__ mean,
                                           const float* __restrict__ var,
                                           unsigned short* __restrict__ W5u,
                                           float* __restrict__ b5) {
    const int b = blockIdx.z;
    const int n0 = blockIdx.x * 64, m0 = blockIdx.y * 64;
    const unsigned short* Va = V1 + (long)b * CCH * NAa;
    const unsigned short* Vb = V2 + (long)b * PAD * NAa;
    const int t = threadIdx.x, w = t >> 6, lane = t & 63, quad = lane >> 4, l16 = lane & 15;
    __shared__ float sred[3 * 4096];      // 48 KB

    f32x4 acc[4][4] = {};
    for (int ks = 0; ks < 32; ++ks) {
        const int k = w * 1024 + ks * 32 + quad * 8;
        bf16x8 af[4], bfr[4];
        #pragma unroll
        for (int i = 0; i < 4; ++i) af[i]  = *(const bf16x8*)(Va + (long)(m0 + i * 16 + l16) * NAa + k);
        #pragma unroll
        for (int j = 0; j < 4; ++j) bfr[j] = *(const bf16x8*)(Vb + (long)(n0 + j * 16 + l16) * NAa + k);
        #pragma unroll
        for (int i = 0; i < 4; ++i)
            #pragma unroll
            for (int j = 0; j < 4; ++j)
                acc[i][j] = __builtin_amdgcn_mfma_f32_16x16x32_bf16(af[i], bfr[j], acc[i][j], 0, 0, 0);
    }
    if (w > 0) {
        #pragma unroll
        for (int i = 0; i < 4; ++i)
            #pragma unroll
            for (int j = 0; j < 4; ++j)
                #pragma unroll
                for (int reg = 0; reg < 4; ++reg)
                    sred[(w - 1) * 4096 + ((i * 4 + j) * 4 + reg) * 64 + lane] = acc[i][j][reg];
    }
    __syncthreads();
    if (w == 0) {
        #pragma unroll
        for (int i = 0; i < 4; ++i)
            #pragma unroll
            for (int j = 0; j < 4; ++j)
                #pragma unroll
                for (int reg = 0; reg < 4; ++reg) {
                    float v = acc[i][j][reg];
                    #pragma unroll
                    for (int rg = 0; rg < 3; ++rg)
                        v += sred[rg * 4096 + ((i * 4 + j) * 4 + reg) * 64 + lane];
                    acc[i][j][reg] = v;
                }
        #pragma unroll
        for (int i = 0; i < 4; ++i) {
            #pragma unroll
            for (int reg = 0; reg < 4; ++reg) {
                const int o = m0 + i * 16 + quad * 4 + reg;
                const float s = gamma[o] * rsqrtf(var[o] + 1e-5f);
                #pragma unroll
                for (int j = 0; j < 4; ++j) {
                    const int c2 = n0 + j * 16 + l16;
                    const float val = acc[i][j][reg] * s * NAinv;
                    if (c2 < CCH)
                        W5u[((long)b * CCH + o) * CCH + c2] = f2bfu(val + (o == c2 ? 1.0f : 0.0f));
                    else if (c2 == CCH)
                        b5[b * CCH + o] = val + s * (qb[o] - mean[o]) + beta[o];
                }
            }
        }
    }
}

// ---- out = W5 @ detect + b5. R3 body verbatim (measured ~42 us).
//      M=256 x N=128 per block (8 waves, 512 thr), detect read exactly once.
//      grid (128, 1, BB), block 512 ----
__global__ __launch_bounds__(512) void k_final(const float* __restrict__ D0,
                                               const unsigned short* __restrict__ W5u,
                                               const float* __restrict__ b5,
                                               float* __restrict__ out) {
    const int z = blockIdx.z;
    const int nb = blockIdx.x * 128;
    const float* D = D0 + (long)z * CCH * NDd;
    float* O = out + (long)z * CCH * NDd;
    const unsigned short* W = W5u + (long)z * CCH * CCH;
    const int t = threadIdx.x, wv = t >> 6, lane = t & 63, quad = lane >> 4, l16 = lane & 15;
    const int mw = (wv >> 1) * 64, nw = (wv & 1) * 64;    // 4 m-tiles x 2 n-tiles
    const int r2 = t >> 4, g = t & 15;                    // staging ids (t < 256 only)
    const bool st = (t < 256);
    // logical row n -> physical row p = (n&7)*16 + (n>>3): write bank = (20g + r2)%32 (2-way, free)
    __shared__ __align__(16) unsigned short lb[2][128][40];

    f32x4 xa[4], xb[4];
    bf16x8 af[2][4], bfr[4];

    auto load_tile = [&](f32x4* x, int kt) {
        const float* base = D + (long)(kt + 2 * r2) * NDd + nb + 8 * g;
        x[0] = *(const f32x4*)(base);
        x[1] = *(const f32x4*)(base + NDd);
        x[2] = *(const f32x4*)(base + 4);
        x[3] = *(const f32x4*)(base + NDd + 4);
    };
    auto write_tile = [&](int buf, const f32x4* x) {
        #pragma unroll
        for (int e2 = 0; e2 < 2; ++e2)
            #pragma unroll
            for (int c = 0; c < 4; ++c) {
                const int n = 8 * g + 4 * e2 + c;
                const int p = ((n & 7) << 4) + (n >> 3);
                const unsigned v = (unsigned)f2bfu(x[2 * e2][c]) |
                                   ((unsigned)f2bfu(x[2 * e2 + 1][c]) << 16);
                *(unsigned*)&lb[buf][p][2 * r2] = v;
            }
    };
    auto loadW = [&](bf16x8* a, int kt) {
        #pragma unroll
        for (int i = 0; i < 4; ++i)
            a[i] = *(const bf16x8*)(W + (long)(mw + i * 16 + l16) * CCH + kt + quad * 8);
    };

    int pj[4];
    #pragma unroll
    for (int j = 0; j < 4; ++j) {
        const int n = nw + j * 16 + l16;
        pj[j] = ((n & 7) << 4) + (n >> 3);
    }

    f32x4 acc[4][4] = {};
    // prologue: tiles 0,1 in flight; W frags for it=0; stage tile0; issue tile2
    if (st) { load_tile(xa, 0); load_tile(xb, 32); }
    loadW(af[0], 0);
    if (st) { write_tile(0, xa); load_tile(xa, 64); }
    #pragma unroll
    for (int it = 0; it < 8; ++it) {
        __syncthreads();
        const int kt = it * 32;
        #pragma unroll
        for (int j = 0; j < 4; ++j)
            bfr[j] = *(const bf16x8*)&lb[it & 1][pj[j]][quad * 8];
        #pragma unroll
        for (int i = 0; i < 4; ++i)
            #pragma unroll
            for (int j = 0; j < 4; ++j)
                acc[i][j] = __builtin_amdgcn_mfma_f32_16x16x32_bf16(af[it & 1][i], bfr[j], acc[i][j], 0, 0, 0);
        if (it < 7) {
            loadW(af[(it + 1) & 1], kt + 32);               // next W frags cross barrier in flight
            if (st) {
                write_tile((it + 1) & 1, (it & 1) ? xa : xb);   // stage tile it+1 (loaded 2 iters ago)
                if (it < 5) load_tile((it & 1) ? xa : xb, (it + 3) * 32);  // issue tile it+3
            }
        }
    }
    #pragma unroll
    for (int i = 0; i < 4; ++i) {
        float bv[4];
        #pragma unroll
        for (int reg = 0; reg < 4; ++reg)
            bv[reg] = b5[z * CCH + mw + i * 16 + quad * 4 + reg];
        #pragma unroll
        for (int j = 0; j < 4; ++j) {
            const int n = nb + nw + j * 16 + l16;
            #pragma unroll
            for (int reg = 0; reg < 4; ++reg)
                O[(long)(mw + i * 16 + quad * 4 + reg) * NDd + n] = acc[i][j][reg] + bv[reg];
        }
    }
}

extern "C" void kernel_launch(void* const* d_in, const int* in_sizes, int n_in,
                              void* d_out, int out_size, void* d_ws, size_t ws_size,
                              hipStream_t stream) {
    const float* detect = (const float*)d_in[0];
    const float* aim    = (const float*)d_in[1];
    const float* g_w    = (const float*)d_in[2];
    const float* g_b    = (const float*)d_in[3];
    const float* th_w   = (const float*)d_in[4];
    const float* th_b   = (const float*)d_in[5];
    const float* phi_w  = (const float*)d_in[6];
    const float* phi_b  = (const float*)d_in[7];
    const float* q_w    = (const float*)d_in[8];
    const float* q_b    = (const float*)d_in[9];
    const float* gamma  = (const float*)d_in[10];
    const float* beta   = (const float*)d_in[11];
    const float* mean   = (const float*)d_in[12];
    const float* var    = (const float*)d_in[13];
    float* out = (float*)d_out;

    unsigned short* us = (unsigned short*)d_ws;
    unsigned short* V1u = us;                               // 4*256*4096 = 4,194,304 us
    unsigned short* V2u = V1u + 4194304;                    // 4*320*4096 = 5,242,880 us
    unsigned short* Phat_u  = V2u + 5242880;                // 256*320 =  81,920 us
    unsigned short* RhatT_u = Phat_u + 81920;               // 320*320 = 102,400 us
    unsigned short* W5u     = RhatT_u + 102400;             // 4*256*256 = 262,144 us
    float* b5 = (float*)(W5u + 262144);                     // 1,024 f  (total ~19.8 MB)

    k_prep<<<dim3((CCH * PAD + PAD * PAD) / 256), dim3(256), 0, stream>>>(
        q_w, g_w, g_b, th_w, th_b, phi_w, phi_b, Phat_u, RhatT_u);
    k_V<<<dim3(NAa / 64, BB), dim3(256), 0, stream>>>(aim, Phat_u, RhatT_u, V1u, V2u);
    k_W<<<dim3(5, 4, BB), dim3(256), 0, stream>>>(V1u, V2u, q_b, gamma, beta, mean, var, W5u, b5);
    k_final<<<dim3(NDd / 128, 1, BB), dim3(512), 0, stream>>>(detect, W5u, b5, out);
}